// Round 10
// baseline (858.882 us; speedup 1.0000x reference)
//
#include <hip/hip_runtime.h>

typedef unsigned short ushort_t;
typedef __attribute__((ext_vector_type(4))) float f32x4;
typedef __attribute__((ext_vector_type(8))) __bf16 bf16x8;
typedef __attribute__((ext_vector_type(4))) __bf16 bf16x4;
typedef __attribute__((ext_vector_type(8))) unsigned short u16x8;
typedef __attribute__((ext_vector_type(4))) unsigned short u16x4;

__device__ __forceinline__ unsigned short f2bf(float f) {
  union { float f; unsigned int u; } v; v.f = f;
  unsigned int u = v.u;
  u += 0x7fffu + ((u >> 16) & 1u);   // round-to-nearest-even
  return (unsigned short)(u >> 16);
}

__device__ __forceinline__ float bf2f(unsigned short h) {
  union { unsigned int u; float f; } v; v.u = ((unsigned int)h) << 16;
  return v.f;
}

__device__ __forceinline__ void gload16(ushort_t* lds, const ushort_t* g) {
  __builtin_amdgcn_global_load_lds(
      (const __attribute__((address_space(1))) unsigned int*)g,
      (__attribute__((address_space(3))) unsigned int*)lds, 16, 0, 0);
}

// ---------------- weight transpose + f32->bf16 convert:  in [R][C] f32 -> out [C][R] bf16
__global__ __launch_bounds__(256)
void transpose_w(const float* __restrict__ in, ushort_t* __restrict__ out, int R, int C) {
  __shared__ float tile[32][33];
  const int t = threadIdx.x;
  const int tx = t & 31, ty = t >> 5;
  const int r0 = blockIdx.x * 32, c0 = blockIdx.y * 32;
#pragma unroll
  for (int i = 0; i < 4; ++i)
    tile[ty + 8 * i][tx] = in[(size_t)(r0 + ty + 8 * i) * C + c0 + tx];
  __syncthreads();
#pragma unroll
  for (int i = 0; i < 4; ++i)
    out[(size_t)(c0 + ty + 8 * i) * R + r0 + tx] = f2bf(tile[tx][ty + 8 * i]);
}

// ---------------- CSR build: histogram, prefix scan, fill
__global__ __launch_bounds__(256)
void count_edges(const int* __restrict__ col, int* __restrict__ cnt, int E) {
  int i = blockIdx.x * 256 + threadIdx.x;
  if (i < E) atomicAdd(&cnt[col[i]], 1);
}

__global__ __launch_bounds__(1024)
void prefix_kernel(const int* __restrict__ cnt, int* __restrict__ start,
                   int* __restrict__ cursor, int N) {
  const int t = threadIdx.x;
  const int chunk = (N + 1023) >> 10;
  const int base = t * chunk;
  int s = 0;
  for (int j = 0; j < chunk; ++j) {
    int i = base + j;
    s += (i < N) ? cnt[i] : 0;
  }
  const int lane = t & 63, wv = t >> 6;
  int scan = s;
#pragma unroll
  for (int o = 1; o < 64; o <<= 1) {
    int up = __shfl_up(scan, o);
    if (lane >= o) scan += up;
  }
  __shared__ int wsum[16];
  if (lane == 63) wsum[wv] = scan;
  __syncthreads();
  if (t == 0) {
    int acc = 0;
#pragma unroll
    for (int i2 = 0; i2 < 16; ++i2) { int v = wsum[i2]; wsum[i2] = acc; acc += v; }
  }
  __syncthreads();
  int run = wsum[wv] + (scan - s);
  for (int j = 0; j < chunk; ++j) {
    int i = base + j;
    if (i < N) {
      start[i] = run; cursor[i] = run;
      run += cnt[i];
    }
  }
}

__global__ __launch_bounds__(256)
void fill_csr(const int* __restrict__ col, int* __restrict__ cursor,
              int* __restrict__ eids, int E) {
  int i = blockIdx.x * 256 + threadIdx.x;
  if (i < E) {
    int p = atomicAdd(&cursor[col[i]], 1);
    eids[p] = i;
  }
}

// ---------------- gather-mean + build h0: block/node, wave-per-edge, float4/lane
__global__ __launch_bounds__(256)
void gather_mean(const float* __restrict__ eattr, const int* __restrict__ start,
                 const int* __restrict__ deg, const int* __restrict__ eids,
                 const float* __restrict__ x, ushort_t* __restrict__ hcat, int N) {
  const int row = blockIdx.x;
  const int t = threadIdx.x;
  const int w = t >> 6, l = t & 63;
  const int s = start[row], d = deg[row];
  const float4* ea4 = (const float4*)eattr;
  float4 sum = make_float4(0.f, 0.f, 0.f, 0.f);
  for (int i = w; i < d; i += 4) {
    int e = eids[s + i];
    float4 v = ea4[(size_t)e * 64 + l];
    sum.x += v.x; sum.y += v.y; sum.z += v.z; sum.w += v.w;
  }
  __shared__ float4 part[4][64];
  part[w][l] = sum;
  __syncthreads();
  hcat[(size_t)row * 2560 + 2304 + t] = f2bf(x[(size_t)row * 256 + t]);
  if (w == 0) {
    float4 a = part[0][l], b = part[1][l], c = part[2][l], dd = part[3][l];
    const float inv = 1.f / fmaxf((float)d, 1.f);
    u16x4 o;
    o[0] = f2bf((a.x + b.x + c.x + dd.x) * inv);
    o[1] = f2bf((a.y + b.y + c.y + dd.y) * inv);
    o[2] = f2bf((a.z + b.z + c.z + dd.z) * inv);
    o[3] = f2bf((a.w + b.w + c.w + dd.w) * inv);
    *(u16x4*)(hcat + (size_t)row * 2560 + 2048 + l * 4) = o;
  }
}

// ---------------- LayerNorm IN PLACE over hcat[:, 0:2048] bf16 (row-local)
__global__ __launch_bounds__(256)
void ln_kernel(ushort_t* __restrict__ hcat, const float* __restrict__ g,
               const float* __restrict__ b) {
  const int row = blockIdx.x;
  const int t = threadIdx.x;
  ushort_t* p = hcat + (size_t)row * 2560 + t * 8;
  u16x8 raw = *(const u16x8*)p;
  float vv[8];
#pragma unroll
  for (int j = 0; j < 8; ++j) vv[j] = bf2f(raw[j]);
  float s = 0.f, ss = 0.f;
#pragma unroll
  for (int j = 0; j < 8; ++j) { s += vv[j]; ss += vv[j] * vv[j]; }
#pragma unroll
  for (int o = 32; o > 0; o >>= 1) {
    s += __shfl_xor(s, o);
    ss += __shfl_xor(ss, o);
  }
  __shared__ float red[8];
  int w = t >> 6, l = t & 63;
  if (l == 0) { red[w] = s; red[4 + w] = ss; }
  __syncthreads();
  s = red[0] + red[1] + red[2] + red[3];
  ss = red[4] + red[5] + red[6] + red[7];
  const float mu = s * (1.f / 2048.f);
  const float var = ss * (1.f / 2048.f) - mu * mu;
  const float rs = rsqrtf(var + 1e-5f);
  float4 g0 = *(const float4*)(g + t * 8);
  float4 g1 = *(const float4*)(g + t * 8 + 4);
  float4 b0 = *(const float4*)(b + t * 8);
  float4 b1 = *(const float4*)(b + t * 8 + 4);
  float gg[8] = {g0.x, g0.y, g0.z, g0.w, g1.x, g1.y, g1.z, g1.w};
  float bb[8] = {b0.x, b0.y, b0.z, b0.w, b1.x, b1.y, b1.z, b1.w};
  u16x8 o8;
#pragma unroll
  for (int j = 0; j < 8; ++j) o8[j] = f2bf((vv[j] - mu) * rs * gg[j] + bb[j]);
  *(u16x8*)p = o8;
}

#define SBAR() do { __builtin_amdgcn_sched_barrier(0); \
                    __builtin_amdgcn_s_barrier(); \
                    __builtin_amdgcn_sched_barrier(0); } while (0)

// ======================= 128x256 8-wave GEMM, BK=32, 2 blocks/CU =======================
// Proven 843us structure (kept for GEMM1 short-K and GEMM4 narrow-N).
template <int RELU, int OUTBF>
__global__ __launch_bounds__(512, 4)
void gemm128(const ushort_t* __restrict__ A, int lda,
             const ushort_t* __restrict__ Bt,
             const float* __restrict__ bias,
             void* __restrict__ Cout, int ldc, int M, int K) {
  __shared__ __align__(16) ushort_t smem[36864];  // 72 KiB = 3 x 24 KiB
  char* sb = (char*)smem;
  const int t = threadIdx.x;

  const int nct = gridDim.x;
  const int nwg = nct * gridDim.y;
  const int flat = blockIdx.y * nct + blockIdx.x;
  const int xcd = flat & 7, loc = flat >> 3;
  const int q = nwg >> 3, r = nwg & 7;
  const int swz = (xcd < r ? xcd * (q + 1) : r * (q + 1) + (xcd - r) * q) + loc;
  const int row0 = (swz / nct) * 128;
  const int col0 = (swz % nct) * 256;

  const int wid = t >> 6, l = t & 63;
  const int wr = wid >> 2, wc = wid & 3;
  const int lr = l & 15, lk = l >> 4;

  const int srow = t >> 2;
  const int scol = ((t & 3) ^ ((t >> 2) & 3)) << 3;
  int ar = row0 + srow; if (ar > M - 1) ar = M - 1;
  const ushort_t* pa  = A + (size_t)ar * lda + scol;
  const ushort_t* pb0 = Bt + (size_t)(col0 + srow) * K + scol;
  const ushort_t* pb1 = pb0 + (size_t)128 * K;
  const int tb = t * 16;

  const int sx = ((lk ^ (lr & 3)) << 4);
  const int arow = (wr * 64 + lr) * 64 + sx;
  const int brow = 8192 + (wc * 64 + lr) * 64 + sx;

  f32x4 acc[4][4] = {};
  const int nk = K >> 5;

  {
    const int k1 = (nk > 1) ? 32 : 0;
    gload16((ushort_t*)(sb + 8192 + tb), pb0);
    gload16((ushort_t*)(sb + 16384 + tb), pb1);
    gload16((ushort_t*)(sb + 0 + tb), pa);
    gload16((ushort_t*)(sb + 24576 + 8192 + tb), pb0 + k1);
    gload16((ushort_t*)(sb + 24576 + 16384 + tb), pb1 + k1);
    gload16((ushort_t*)(sb + 24576 + 0 + tb), pa + k1);
  }
  asm volatile("s_waitcnt vmcnt(3)" ::: "memory");
  SBAR();

  int cO = 0, sO = 49152;
  for (int k = 0; k < nk; ++k) {
    const int kc2 = ((k + 2 < nk) ? k + 2 : nk - 1) << 5;

    bf16x8 a[4], b[4];
#pragma unroll
    for (int m = 0; m < 4; ++m)
      a[m] = *(const bf16x8*)(sb + cO + arow + m * 1024);
#pragma unroll
    for (int n = 0; n < 4; ++n)
      b[n] = *(const bf16x8*)(sb + cO + brow + n * 1024);
    gload16((ushort_t*)(sb + sO + 8192 + tb), pb0 + kc2);
    gload16((ushort_t*)(sb + sO + 16384 + tb), pb1 + kc2);
    gload16((ushort_t*)(sb + sO + 0 + tb), pa + kc2);

    __builtin_amdgcn_s_setprio(1);
#pragma unroll
    for (int m = 0; m < 4; ++m)
#pragma unroll
      for (int n = 0; n < 4; ++n)
        acc[m][n] = __builtin_amdgcn_mfma_f32_16x16x32_bf16(b[n], a[m], acc[m][n], 0, 0, 0);
    __builtin_amdgcn_s_setprio(0);

    asm volatile("s_waitcnt vmcnt(3)" ::: "memory");
    SBAR();

    cO = (cO == 49152) ? 0 : cO + 24576;
    sO = (sO == 49152) ? 0 : sO + 24576;
  }
  asm volatile("s_waitcnt vmcnt(0)" ::: "memory");

#pragma unroll
  for (int mi = 0; mi < 4; ++mi) {
    const int orow = row0 + wr * 64 + mi * 16 + lr;
    if (orow < M) {
#pragma unroll
      for (int nj = 0; nj < 4; ++nj) {
        const int cb = col0 + wc * 64 + nj * 16 + lk * 4;
        const float4 bv = *(const float4*)(bias + cb);
        f32x4 v = acc[mi][nj];
        float o0 = v[0] + bv.x, o1 = v[1] + bv.y, o2 = v[2] + bv.z, o3 = v[3] + bv.w;
        if (RELU) {
          o0 = fmaxf(o0, 0.f); o1 = fmaxf(o1, 0.f);
          o2 = fmaxf(o2, 0.f); o3 = fmaxf(o3, 0.f);
        }
        if (OUTBF) {
          bf16x4 o;
          o[0] = (__bf16)o0; o[1] = (__bf16)o1; o[2] = (__bf16)o2; o[3] = (__bf16)o3;
          *(bf16x4*)((ushort_t*)Cout + (size_t)orow * ldc + cb) = o;
        } else {
          float4 ov = make_float4(o0, o1, o2, o3);
          *(float4*)((float*)Cout + (size_t)orow * ldc + cb) = ov;
        }
      }
    }
  }
}

// ======================= 256x256 8-wave GEMM, BK=32, 1 block/CU =======================
// Per-wave output 128x64 (acc[8][4] = 128 VGPR) -> A-tile reuse doubles: LDS traffic
// 96KB per 4.2MF (22.9 B/MF, 0.75x of gemm128) ~ balanced with MFMA (~1100 cyc/tile).
// Same proven 3-buf FIFO: single barrier + counted vmcnt(4)/K-tile (4 loads/tile).
// ~196 VGPR -> __launch_bounds__(512,2): 8 waves/CU (2/SIMD), m201-precedent occupancy.
template <int RELU, int OUTBF>
__global__ __launch_bounds__(512, 2)
void gemm256(const ushort_t* __restrict__ A, int lda,
             const ushort_t* __restrict__ Bt,
             const float* __restrict__ bias,
             void* __restrict__ Cout, int ldc, int M, int K) {
  __shared__ __align__(16) ushort_t smem[49152];  // 96 KiB = 3 x 32 KiB
  char* sb = (char*)smem;
  const int t = threadIdx.x;

  const int nct = gridDim.x;
  const int nwg = nct * gridDim.y;
  const int flat = blockIdx.y * nct + blockIdx.x;
  const int xcd = flat & 7, loc = flat >> 3;
  const int q = nwg >> 3, r = nwg & 7;
  const int swz = (xcd < r ? xcd * (q + 1) : r * (q + 1) + (xcd - r) * q) + loc;
  const int row0 = (swz / nct) * 256;
  const int col0 = (swz % nct) * 256;

  const int wid = t >> 6, l = t & 63;
  const int wr = wid >> 2, wc = wid & 3;   // 2 M-groups x 4 N-groups; per-wave 128x64
  const int lr = l & 15, lk = l >> 4;

  // ---- staging: A rows srow & srow+128, B rows srow & srow+128; swizzled source col
  const int srow = t >> 2;
  const int scol = ((t & 3) ^ ((t >> 2) & 3)) << 3;
  int ar0 = row0 + srow;        if (ar0 > M - 1) ar0 = M - 1;
  int ar1 = row0 + 128 + srow;  if (ar1 > M - 1) ar1 = M - 1;
  const ushort_t* pa0 = A + (size_t)ar0 * lda + scol;
  const ushort_t* pa1 = A + (size_t)ar1 * lda + scol;
  const ushort_t* pb0 = Bt + (size_t)(col0 + srow) * K + scol;
  const ushort_t* pb1 = pb0 + (size_t)128 * K;
  const int tb = t * 16;

  // ---- reader offsets: row pitch 64B, slot xor (row&3) == (lr&3)
  const int sx = ((lk ^ (lr & 3)) << 4);
  const int arow = (wr * 128 + lr) * 64 + sx;            // + m*1024, m=0..7
  const int brow = 16384 + (wc * 64 + lr) * 64 + sx;     // + n*1024, n=0..3

  f32x4 acc[8][4] = {};
  const int nk = K >> 5;

  // ---- prologue: stage tiles 0,1 into bufs 0,1 (4 loads each); drain to tile0
  {
    const int k1 = (nk > 1) ? 32 : 0;
    gload16((ushort_t*)(sb + 0 + tb), pa0);
    gload16((ushort_t*)(sb + 8192 + tb), pa1);
    gload16((ushort_t*)(sb + 16384 + tb), pb0);
    gload16((ushort_t*)(sb + 24576 + tb), pb1);
    gload16((ushort_t*)(sb + 32768 + 0 + tb), pa0 + k1);
    gload16((ushort_t*)(sb + 32768 + 8192 + tb), pa1 + k1);
    gload16((ushort_t*)(sb + 32768 + 16384 + tb), pb0 + k1);
    gload16((ushort_t*)(sb + 32768 + 24576 + tb), pb1 + k1);
  }
  asm volatile("s_waitcnt vmcnt(4)" ::: "memory");
  SBAR();

  int cO = 0, sO = 65536;  // current buf, stage buf = (k+2)%3
  for (int k = 0; k < nk; ++k) {
    const int kc2 = ((k + 2 < nk) ? k + 2 : nk - 1) << 5;

    bf16x8 a[8], b[4];
#pragma unroll
    for (int m = 0; m < 8; ++m)
      a[m] = *(const bf16x8*)(sb + cO + arow + m * 1024);
#pragma unroll
    for (int n = 0; n < 4; ++n)
      b[n] = *(const bf16x8*)(sb + cO + brow + n * 1024);
    gload16((ushort_t*)(sb + sO + 0 + tb), pa0 + kc2);
    gload16((ushort_t*)(sb + sO + 8192 + tb), pa1 + kc2);
    gload16((ushort_t*)(sb + sO + 16384 + tb), pb0 + kc2);
    gload16((ushort_t*)(sb + sO + 24576 + tb), pb1 + kc2);

    __builtin_amdgcn_s_setprio(1);
#pragma unroll
    for (int m = 0; m < 8; ++m)
#pragma unroll
      for (int n = 0; n < 4; ++n)
        acc[m][n] = __builtin_amdgcn_mfma_f32_16x16x32_bf16(b[n], a[m], acc[m][n], 0, 0, 0);
    __builtin_amdgcn_s_setprio(0);

    asm volatile("s_waitcnt vmcnt(4)" ::: "memory");
    SBAR();

    cO = (cO == 65536) ? 0 : cO + 32768;
    sO = (sO == 65536) ? 0 : sO + 32768;
  }
  asm volatile("s_waitcnt vmcnt(0)" ::: "memory");

  // ---- epilogue: swapped layout -> per-lane row (lr) x 4 consecutive cols
#pragma unroll
  for (int mi = 0; mi < 8; ++mi) {
    const int orow = row0 + wr * 128 + mi * 16 + lr;
    if (orow < M) {
#pragma unroll
      for (int nj = 0; nj < 4; ++nj) {
        const int cb = col0 + wc * 64 + nj * 16 + lk * 4;
        const float4 bv = *(const float4*)(bias + cb);
        f32x4 v = acc[mi][nj];
        float o0 = v[0] + bv.x, o1 = v[1] + bv.y, o2 = v[2] + bv.z, o3 = v[3] + bv.w;
        if (RELU) {
          o0 = fmaxf(o0, 0.f); o1 = fmaxf(o1, 0.f);
          o2 = fmaxf(o2, 0.f); o3 = fmaxf(o3, 0.f);
        }
        if (OUTBF) {
          bf16x4 o;
          o[0] = (__bf16)o0; o[1] = (__bf16)o1; o[2] = (__bf16)o2; o[3] = (__bf16)o3;
          *(bf16x4*)((ushort_t*)Cout + (size_t)orow * ldc + cb) = o;
        } else {
          float4 ov = make_float4(o0, o1, o2, o3);
          *(float4*)((float*)Cout + (size_t)orow * ldc + cb) = ov;
        }
      }
    }
  }
}

extern "C" void kernel_launch(void* const* d_in, const int* in_sizes, int n_in,
                              void* d_out, int out_size, void* d_ws, size_t ws_size,
                              hipStream_t stream) {
  (void)n_in; (void)out_size; (void)ws_size;
  const float* x     = (const float*)d_in[0];
  const int*   eidx  = (const int*)d_in[1];
  const float* eattr = (const float*)d_in[2];
  const float* W1 = (const float*)d_in[6];
  const float* b1 = (const float*)d_in[7];
  const float* W3 = (const float*)d_in[8];
  const float* b3 = (const float*)d_in[9];
  const float* lng = (const float*)d_in[10];
  const float* lnb = (const float*)d_in[11];
  const float* W6 = (const float*)d_in[12];
  const float* b6 = (const float*)d_in[13];
  const float* W8 = (const float*)d_in[14];
  const float* b8 = (const float*)d_in[15];

  const int N = in_sizes[0] / 256;  // 20000
  const int E = in_sizes[2] / 256;  // 640000
  const int* col = eidx + E;        // edge_index[1]

  char* ws = (char*)d_ws;
  size_t off = 0;
  ushort_t* hcat = (ushort_t*)(ws + off);  off += (size_t)N * 2560 * 2;  // [h5/h4 | agg | x] bf16
  ushort_t* h2   = (ushort_t*)(ws + off);  off += (size_t)N * 2048 * 2;  // also reused as h7
  ushort_t* W1t = (ushort_t*)(ws + off);   off += (size_t)2048 * 512 * 2;
  ushort_t* W3t = (ushort_t*)(ws + off);   off += (size_t)2048 * 2048 * 2;
  ushort_t* W6t = (ushort_t*)(ws + off);   off += (size_t)2048 * 2560 * 2;
  ushort_t* W8t = (ushort_t*)(ws + off);   off += (size_t)512 * 2048 * 2;
  int* deg    = (int*)(ws + off);  off += (size_t)N * 4;
  int* startp = (int*)(ws + off);  off += (size_t)N * 4;
  int* cursor = (int*)(ws + off);  off += (size_t)N * 4;
  int* eids   = (int*)(ws + off);  off += (size_t)E * 4;

  hipMemsetAsync(deg, 0, (size_t)N * 4, stream);

  transpose_w<<<dim3(512 / 32, 2048 / 32), 256, 0, stream>>>(W1, W1t, 512, 2048);
  transpose_w<<<dim3(2048 / 32, 2048 / 32), 256, 0, stream>>>(W3, W3t, 2048, 2048);
  transpose_w<<<dim3(2560 / 32, 2048 / 32), 256, 0, stream>>>(W6, W6t, 2560, 2048);
  transpose_w<<<dim3(2048 / 32, 512 / 32), 256, 0, stream>>>(W8, W8t, 2048, 512);

  // CSR build + gather-mean
  count_edges<<<(E + 255) / 256, 256, 0, stream>>>(col, deg, E);
  prefix_kernel<<<1, 1024, 0, stream>>>(deg, startp, cursor, N);
  fill_csr<<<(E + 255) / 256, 256, 0, stream>>>(col, cursor, eids, E);
  gather_mean<<<N, 256, 0, stream>>>(eattr, startp, deg, eids, x, hcat, N);

  const int Mt128 = (N + 127) / 128;   // 157
  const int Mt256 = (N + 255) / 256;   // 79
  // GEMM1: h0 [N,512] @ W1 -> h2 bf16 (ReLU)  [short K: proven gemm128]
  gemm128<1, 1><<<dim3(8, Mt128), 512, 0, stream>>>(hcat + 2048, 2560, W1t, b1, h2, 2048, N, 512);
  // GEMM2: h2 @ W3 -> h4 bf16 (ReLU) into hcat[:, 0:2048]  [new gemm256]
  gemm256<1, 1><<<dim3(8, Mt256), 512, 0, stream>>>(h2, 2048, W3t, b3, hcat, 2560, N, 2048);
  // LN in place on hcat[:, 0:2048]
  ln_kernel<<<N, 256, 0, stream>>>(hcat, lng, lnb);
  // GEMM3: hcat [N,2560] @ W6 -> h7 bf16 (ReLU)  [new gemm256]
  gemm256<1, 1><<<dim3(8, Mt256), 512, 0, stream>>>(hcat, 2560, W6t, b6, h2, 2048, N, 2560);
  // GEMM4: h7 @ W8 -> out f32  [narrow N: proven gemm128]
  gemm128<0, 0><<<dim3(2, Mt128), 512, 0, stream>>>(h2, 2048, W8t, b8, (float*)d_out, 512, N, 2048);
}

// Round 11
// 822.900 us; speedup vs baseline: 1.0437x; 1.0437x over previous
//
#include <hip/hip_runtime.h>

typedef unsigned short ushort_t;
typedef __attribute__((ext_vector_type(4))) float f32x4;
typedef __attribute__((ext_vector_type(8))) __bf16 bf16x8;
typedef __attribute__((ext_vector_type(4))) __bf16 bf16x4;
typedef __attribute__((ext_vector_type(8))) unsigned short u16x8;
typedef __attribute__((ext_vector_type(4))) unsigned short u16x4;

__device__ __forceinline__ unsigned short f2bf(float f) {
  union { float f; unsigned int u; } v; v.f = f;
  unsigned int u = v.u;
  u += 0x7fffu + ((u >> 16) & 1u);   // round-to-nearest-even
  return (unsigned short)(u >> 16);
}

__device__ __forceinline__ float bf2f(unsigned short h) {
  union { unsigned int u; float f; } v; v.u = ((unsigned int)h) << 16;
  return v.f;
}

__device__ __forceinline__ void gload16(ushort_t* lds, const ushort_t* g) {
  __builtin_amdgcn_global_load_lds(
      (const __attribute__((address_space(1))) unsigned int*)g,
      (__attribute__((address_space(3))) unsigned int*)lds, 16, 0, 0);
}

// ---------------- fused prep: 4 weight transposes (f32 [R][C] -> bf16 [C][R]) + edge histogram
// block ranges: [0,1024) W1 | [1024,5120) W3 | [5120,10240) W6 | [10240,11264) W8 | rest: count
__global__ __launch_bounds__(256)
void prep_kernel(const float* __restrict__ W1, const float* __restrict__ W3,
                 const float* __restrict__ W6, const float* __restrict__ W8,
                 ushort_t* __restrict__ W1t, ushort_t* __restrict__ W3t,
                 ushort_t* __restrict__ W6t, ushort_t* __restrict__ W8t,
                 const int* __restrict__ col, int* __restrict__ deg, int E) {
  const int bid = blockIdx.x;
  const int t = threadIdx.x;
  if (bid >= 11264) {
    int i = (bid - 11264) * 256 + t;
    if (i < E) atomicAdd(&deg[col[i]], 1);
    return;
  }
  const float* in; ushort_t* out; int R, C, lb;
  if (bid < 1024)       { in = W1; out = W1t; R = 512;  C = 2048; lb = bid; }
  else if (bid < 5120)  { in = W3; out = W3t; R = 2048; C = 2048; lb = bid - 1024; }
  else if (bid < 10240) { in = W6; out = W6t; R = 2560; C = 2048; lb = bid - 5120; }
  else                  { in = W8; out = W8t; R = 2048; C = 512;  lb = bid - 10240; }
  __shared__ float tile[32][33];
  const int tx = t & 31, ty = t >> 5;
  const int nrt = R >> 5;
  const int r0 = (lb % nrt) * 32, c0 = (lb / nrt) * 32;
#pragma unroll
  for (int i = 0; i < 4; ++i)
    tile[ty + 8 * i][tx] = in[(size_t)(r0 + ty + 8 * i) * C + c0 + tx];
  __syncthreads();
#pragma unroll
  for (int i = 0; i < 4; ++i)
    out[(size_t)(c0 + ty + 8 * i) * R + r0 + tx] = f2bf(tile[tx][ty + 8 * i]);
}

// ---------------- CSR build: prefix scan, fill
__global__ __launch_bounds__(1024)
void prefix_kernel(const int* __restrict__ cnt, int* __restrict__ start,
                   int* __restrict__ cursor, int N) {
  const int t = threadIdx.x;
  const int chunk = (N + 1023) >> 10;
  const int base = t * chunk;
  int s = 0;
  for (int j = 0; j < chunk; ++j) {
    int i = base + j;
    s += (i < N) ? cnt[i] : 0;
  }
  const int lane = t & 63, wv = t >> 6;
  int scan = s;
#pragma unroll
  for (int o = 1; o < 64; o <<= 1) {
    int up = __shfl_up(scan, o);
    if (lane >= o) scan += up;
  }
  __shared__ int wsum[16];
  if (lane == 63) wsum[wv] = scan;
  __syncthreads();
  if (t == 0) {
    int acc = 0;
#pragma unroll
    for (int i2 = 0; i2 < 16; ++i2) { int v = wsum[i2]; wsum[i2] = acc; acc += v; }
  }
  __syncthreads();
  int run = wsum[wv] + (scan - s);
  for (int j = 0; j < chunk; ++j) {
    int i = base + j;
    if (i < N) {
      start[i] = run; cursor[i] = run;
      run += cnt[i];
    }
  }
}

__global__ __launch_bounds__(256)
void fill_csr(const int* __restrict__ col, int* __restrict__ cursor,
              int* __restrict__ eids, int E) {
  int i = blockIdx.x * 256 + threadIdx.x;
  if (i < E) {
    int p = atomicAdd(&cursor[col[i]], 1);
    eids[p] = i;
  }
}

// ---------------- gather-mean + build h0: block/node; each wave owns a CONTIGUOUS
// quarter of the edge list, unrolled x4 -> 4 independent 1KB row loads in flight.
__global__ __launch_bounds__(256)
void gather_mean(const float* __restrict__ eattr, const int* __restrict__ start,
                 const int* __restrict__ deg, const int* __restrict__ eids,
                 const float* __restrict__ x, ushort_t* __restrict__ hcat, int N) {
  const int row = blockIdx.x;
  const int t = threadIdx.x;
  const int w = t >> 6, l = t & 63;
  const int s = start[row], d = deg[row];
  const float4* ea4 = (const float4*)eattr;
  float4 sum = make_float4(0.f, 0.f, 0.f, 0.f);
  const int chunk = (d + 3) >> 2;
  const int i0 = w * chunk;
  const int i1 = (d < i0 + chunk) ? d : i0 + chunk;
  int i = i0;
  for (; i + 4 <= i1; i += 4) {
    int e0 = eids[s + i], e1 = eids[s + i + 1], e2 = eids[s + i + 2], e3 = eids[s + i + 3];
    float4 v0 = ea4[(size_t)e0 * 64 + l];
    float4 v1 = ea4[(size_t)e1 * 64 + l];
    float4 v2 = ea4[(size_t)e2 * 64 + l];
    float4 v3 = ea4[(size_t)e3 * 64 + l];
    sum.x += v0.x + v1.x + v2.x + v3.x;
    sum.y += v0.y + v1.y + v2.y + v3.y;
    sum.z += v0.z + v1.z + v2.z + v3.z;
    sum.w += v0.w + v1.w + v2.w + v3.w;
  }
  for (; i < i1; ++i) {
    float4 v = ea4[(size_t)eids[s + i] * 64 + l];
    sum.x += v.x; sum.y += v.y; sum.z += v.z; sum.w += v.w;
  }
  __shared__ float4 part[4][64];
  part[w][l] = sum;
  __syncthreads();
  hcat[(size_t)row * 2560 + 2304 + t] = f2bf(x[(size_t)row * 256 + t]);
  if (w == 0) {
    float4 a = part[0][l], b = part[1][l], c = part[2][l], dd = part[3][l];
    const float inv = 1.f / fmaxf((float)d, 1.f);
    u16x4 o;
    o[0] = f2bf((a.x + b.x + c.x + dd.x) * inv);
    o[1] = f2bf((a.y + b.y + c.y + dd.y) * inv);
    o[2] = f2bf((a.z + b.z + c.z + dd.z) * inv);
    o[3] = f2bf((a.w + b.w + c.w + dd.w) * inv);
    *(u16x4*)(hcat + (size_t)row * 2560 + 2048 + l * 4) = o;
  }
}

// ---------------- LayerNorm IN PLACE over hcat[:, 0:2048] bf16 (row-local)
__global__ __launch_bounds__(256)
void ln_kernel(ushort_t* __restrict__ hcat, const float* __restrict__ g,
               const float* __restrict__ b) {
  const int row = blockIdx.x;
  const int t = threadIdx.x;
  ushort_t* p = hcat + (size_t)row * 2560 + t * 8;
  u16x8 raw = *(const u16x8*)p;
  float vv[8];
#pragma unroll
  for (int j = 0; j < 8; ++j) vv[j] = bf2f(raw[j]);
  float s = 0.f, ss = 0.f;
#pragma unroll
  for (int j = 0; j < 8; ++j) { s += vv[j]; ss += vv[j] * vv[j]; }
#pragma unroll
  for (int o = 32; o > 0; o >>= 1) {
    s += __shfl_xor(s, o);
    ss += __shfl_xor(ss, o);
  }
  __shared__ float red[8];
  int w = t >> 6, l = t & 63;
  if (l == 0) { red[w] = s; red[4 + w] = ss; }
  __syncthreads();
  s = red[0] + red[1] + red[2] + red[3];
  ss = red[4] + red[5] + red[6] + red[7];
  const float mu = s * (1.f / 2048.f);
  const float var = ss * (1.f / 2048.f) - mu * mu;
  const float rs = rsqrtf(var + 1e-5f);
  float4 g0 = *(const float4*)(g + t * 8);
  float4 g1 = *(const float4*)(g + t * 8 + 4);
  float4 b0 = *(const float4*)(b + t * 8);
  float4 b1 = *(const float4*)(b + t * 8 + 4);
  float gg[8] = {g0.x, g0.y, g0.z, g0.w, g1.x, g1.y, g1.z, g1.w};
  float bb[8] = {b0.x, b0.y, b0.z, b0.w, b1.x, b1.y, b1.z, b1.w};
  u16x8 o8;
#pragma unroll
  for (int j = 0; j < 8; ++j) o8[j] = f2bf((vv[j] - mu) * rs * gg[j] + bb[j]);
  *(u16x8*)p = o8;
}

// ======================= 128x256 8-wave GEMM, BK=32, 2 blocks/CU =======================
// Measured-best structure (843us). 512 threads = 8 waves (2M x 4N), per-wave C = 64x64.
// LDS: 3 bufs x (A 128x32 | B 256x32) bf16 = 72 KiB -> 2 blocks/CU.
// Single barrier + single counted vmcnt(3) per K-tile. Staging gloads issued BEFORE
// the LDS frag reads (stage buffer sO was fully consumed behind the previous barrier
// -> no race; earlier VMEM issue = more overlap). Swapped MFMA operands -> per-lane
// acc f32x4 = one M-row x 4 consecutive N-cols => vectorized C-stores.

#define SBAR() do { __builtin_amdgcn_sched_barrier(0); \
                    __builtin_amdgcn_s_barrier(); \
                    __builtin_amdgcn_sched_barrier(0); } while (0)

template <int RELU, int OUTBF>
__global__ __launch_bounds__(512, 4)
void gemm128(const ushort_t* __restrict__ A, int lda,
             const ushort_t* __restrict__ Bt,
             const float* __restrict__ bias,
             void* __restrict__ Cout, int ldc, int M, int K) {
  __shared__ __align__(16) ushort_t smem[36864];  // 72 KiB = 3 x 24 KiB
  char* sb = (char*)smem;
  const int t = threadIdx.x;

  // block remap: col-fastest + bijective XCD chunks
  const int nct = gridDim.x;
  const int nwg = nct * gridDim.y;
  const int flat = blockIdx.y * nct + blockIdx.x;
  const int xcd = flat & 7, loc = flat >> 3;
  const int q = nwg >> 3, r = nwg & 7;
  const int swz = (xcd < r ? xcd * (q + 1) : r * (q + 1) + (xcd - r) * q) + loc;
  const int row0 = (swz / nct) * 128;
  const int col0 = (swz % nct) * 256;

  const int wid = t >> 6, l = t & 63;
  const int wr = wid >> 2, wc = wid & 3;   // 2 x 4 waves, per-wave 64x64
  const int lr = l & 15, lk = l >> 4;

  // ---- staging: thread t -> row t>>2 (0..127), 16B slot t&3; source col pre-swizzled
  const int srow = t >> 2;
  const int scol = ((t & 3) ^ ((t >> 2) & 3)) << 3;   // elems
  int ar = row0 + srow; if (ar > M - 1) ar = M - 1;
  const ushort_t* pa  = A + (size_t)ar * lda + scol;
  const ushort_t* pb0 = Bt + (size_t)(col0 + srow) * K + scol;
  const ushort_t* pb1 = pb0 + (size_t)128 * K;
  const int tb = t * 16;

  // ---- reader offsets: row pitch 64B, slot xor (row&3) == (lr&3)
  const int sx = ((lk ^ (lr & 3)) << 4);
  const int arow = (wr * 64 + lr) * 64 + sx;            // + m*1024
  const int brow = 8192 + (wc * 64 + lr) * 64 + sx;     // + n*1024

  f32x4 acc[4][4] = {};
  const int nk = K >> 5;

  // ---- prologue: tile0 {B0,B1,A}, tile1 {B0,B1,A}; drain to tile0 (vmcnt(3))
  {
    const int k1 = (nk > 1) ? 32 : 0;
    gload16((ushort_t*)(sb + 8192 + tb), pb0);
    gload16((ushort_t*)(sb + 16384 + tb), pb1);
    gload16((ushort_t*)(sb + 0 + tb), pa);
    gload16((ushort_t*)(sb + 24576 + 8192 + tb), pb0 + k1);
    gload16((ushort_t*)(sb + 24576 + 16384 + tb), pb1 + k1);
    gload16((ushort_t*)(sb + 24576 + 0 + tb), pa + k1);
  }
  asm volatile("s_waitcnt vmcnt(3)" ::: "memory");
  SBAR();

  int cO = 0, sO = 49152;  // current buf, stage buf = (k+2)%3
  for (int k = 0; k < nk; ++k) {
    const int kc2 = ((k + 2 < nk) ? k + 2 : nk - 1) << 5;  // elem offset

    // stage first (earlier VMEM issue; sO consumed behind previous barrier)
    gload16((ushort_t*)(sb + sO + 8192 + tb), pb0 + kc2);
    gload16((ushort_t*)(sb + sO + 16384 + tb), pb1 + kc2);
    gload16((ushort_t*)(sb + sO + 0 + tb), pa + kc2);

    bf16x8 a[4], b[4];
#pragma unroll
    for (int m = 0; m < 4; ++m)
      a[m] = *(const bf16x8*)(sb + cO + arow + m * 1024);
#pragma unroll
    for (int n = 0; n < 4; ++n)
      b[n] = *(const bf16x8*)(sb + cO + brow + n * 1024);

    __builtin_amdgcn_s_setprio(1);
#pragma unroll
    for (int m = 0; m < 4; ++m)
#pragma unroll
      for (int n = 0; n < 4; ++n)
        acc[m][n] = __builtin_amdgcn_mfma_f32_16x16x32_bf16(b[n], a[m], acc[m][n], 0, 0, 0);
    __builtin_amdgcn_s_setprio(0);

    asm volatile("s_waitcnt vmcnt(3)" ::: "memory");
    SBAR();

    cO = (cO == 49152) ? 0 : cO + 24576;
    sO = (sO == 49152) ? 0 : sO + 24576;
  }
  asm volatile("s_waitcnt vmcnt(0)" ::: "memory");  // retire dangling prefetches

  // ---- epilogue: swapped layout -> per-lane row (lr) x 4 consecutive cols (lk*4+reg)
#pragma unroll
  for (int mi = 0; mi < 4; ++mi) {
    const int orow = row0 + wr * 64 + mi * 16 + lr;
    if (orow < M) {
#pragma unroll
      for (int nj = 0; nj < 4; ++nj) {
        const int cb = col0 + wc * 64 + nj * 16 + lk * 4;
        const float4 bv = *(const float4*)(bias + cb);
        f32x4 v = acc[mi][nj];
        float o0 = v[0] + bv.x, o1 = v[1] + bv.y, o2 = v[2] + bv.z, o3 = v[3] + bv.w;
        if (RELU) {
          o0 = fmaxf(o0, 0.f); o1 = fmaxf(o1, 0.f);
          o2 = fmaxf(o2, 0.f); o3 = fmaxf(o3, 0.f);
        }
        if (OUTBF) {
          bf16x4 o;
          o[0] = (__bf16)o0; o[1] = (__bf16)o1; o[2] = (__bf16)o2; o[3] = (__bf16)o3;
          *(bf16x4*)((ushort_t*)Cout + (size_t)orow * ldc + cb) = o;
        } else {
          float4 ov = make_float4(o0, o1, o2, o3);
          *(float4*)((float*)Cout + (size_t)orow * ldc + cb) = ov;
        }
      }
    }
  }
}

extern "C" void kernel_launch(void* const* d_in, const int* in_sizes, int n_in,
                              void* d_out, int out_size, void* d_ws, size_t ws_size,
                              hipStream_t stream) {
  (void)n_in; (void)out_size; (void)ws_size;
  const float* x     = (const float*)d_in[0];
  const int*   eidx  = (const int*)d_in[1];
  const float* eattr = (const float*)d_in[2];
  const float* W1 = (const float*)d_in[6];
  const float* b1 = (const float*)d_in[7];
  const float* W3 = (const float*)d_in[8];
  const float* b3 = (const float*)d_in[9];
  const float* lng = (const float*)d_in[10];
  const float* lnb = (const float*)d_in[11];
  const float* W6 = (const float*)d_in[12];
  const float* b6 = (const float*)d_in[13];
  const float* W8 = (const float*)d_in[14];
  const float* b8 = (const float*)d_in[15];

  const int N = in_sizes[0] / 256;  // 20000
  const int E = in_sizes[2] / 256;  // 640000
  const int* col = eidx + E;        // edge_index[1]

  char* ws = (char*)d_ws;
  size_t off = 0;
  ushort_t* hcat = (ushort_t*)(ws + off);  off += (size_t)N * 2560 * 2;  // [h5/h4 | agg | x] bf16
  ushort_t* h2   = (ushort_t*)(ws + off);  off += (size_t)N * 2048 * 2;  // also reused as h7
  ushort_t* W1t = (ushort_t*)(ws + off);   off += (size_t)2048 * 512 * 2;
  ushort_t* W3t = (ushort_t*)(ws + off);   off += (size_t)2048 * 2048 * 2;
  ushort_t* W6t = (ushort_t*)(ws + off);   off += (size_t)2048 * 2560 * 2;
  ushort_t* W8t = (ushort_t*)(ws + off);   off += (size_t)512 * 2048 * 2;
  int* deg    = (int*)(ws + off);  off += (size_t)N * 4;
  int* startp = (int*)(ws + off);  off += (size_t)N * 4;
  int* cursor = (int*)(ws + off);  off += (size_t)N * 4;
  int* eids   = (int*)(ws + off);  off += (size_t)E * 4;

  hipMemsetAsync(deg, 0, (size_t)N * 4, stream);

  // fused: 4 weight transposes + edge histogram
  const int cntBlocks = (E + 255) / 256;
  prep_kernel<<<11264 + cntBlocks, 256, 0, stream>>>(W1, W3, W6, W8, W1t, W3t, W6t, W8t,
                                                     col, deg, E);
  prefix_kernel<<<1, 1024, 0, stream>>>(deg, startp, cursor, N);
  fill_csr<<<cntBlocks, 256, 0, stream>>>(col, cursor, eids, E);
  gather_mean<<<N, 256, 0, stream>>>(eattr, startp, deg, eids, x, hcat, N);

  const int Mt = (N + 127) / 128;   // 157
  // GEMM1: h0 [N,512] @ W1 -> h2 bf16 (ReLU)
  gemm128<1, 1><<<dim3(8, Mt), 512, 0, stream>>>(hcat + 2048, 2560, W1t, b1, h2, 2048, N, 512);
  // GEMM2: h2 @ W3 -> h4 bf16 (ReLU) DIRECTLY into hcat[:, 0:2048]
  gemm128<1, 1><<<dim3(8, Mt), 512, 0, stream>>>(h2, 2048, W3t, b3, hcat, 2560, N, 2048);
  // LN in place on hcat[:, 0:2048]
  ln_kernel<<<N, 256, 0, stream>>>(hcat, lng, lnb);
  // GEMM3: hcat [N,2560] @ W6 -> h7 bf16 (ReLU), reuse h2 buffer
  gemm128<1, 1><<<dim3(8, Mt), 512, 0, stream>>>(hcat, 2560, W6t, b6, h2, 2048, N, 2560);
  // GEMM4: h7 @ W8 -> out f32
  gemm128<0, 0><<<dim3(2, Mt), 512, 0, stream>>>(h2, 2048, W8t, b8, (float*)d_out, 512, N, 2048);
}

// Round 12
// 820.585 us; speedup vs baseline: 1.0467x; 1.0028x over previous
//
#include <hip/hip_runtime.h>

typedef unsigned short ushort_t;
typedef __attribute__((ext_vector_type(4))) float f32x4;
typedef __attribute__((ext_vector_type(8))) __bf16 bf16x8;
typedef __attribute__((ext_vector_type(4))) __bf16 bf16x4;
typedef __attribute__((ext_vector_type(8))) unsigned short u16x8;
typedef __attribute__((ext_vector_type(4))) unsigned short u16x4;

__device__ __forceinline__ unsigned short f2bf(float f) {
  union { float f; unsigned int u; } v; v.f = f;
  unsigned int u = v.u;
  u += 0x7fffu + ((u >> 16) & 1u);   // round-to-nearest-even
  return (unsigned short)(u >> 16);
}

__device__ __forceinline__ float bf2f(unsigned short h) {
  union { unsigned int u; float f; } v; v.u = ((unsigned int)h) << 16;
  return v.f;
}

__device__ __forceinline__ void gload16(ushort_t* lds, const ushort_t* g) {
  __builtin_amdgcn_global_load_lds(
      (const __attribute__((address_space(1))) unsigned int*)g,
      (__attribute__((address_space(3))) unsigned int*)lds, 16, 0, 0);
}

// ---------------- fused prep: 4 weight transposes (f32 [R][C] -> bf16 [C][R]) + edge histogram
__global__ __launch_bounds__(256)
void prep_kernel(const float* __restrict__ W1, const float* __restrict__ W3,
                 const float* __restrict__ W6, const float* __restrict__ W8,
                 ushort_t* __restrict__ W1t, ushort_t* __restrict__ W3t,
                 ushort_t* __restrict__ W6t, ushort_t* __restrict__ W8t,
                 const int* __restrict__ col, int* __restrict__ deg, int E) {
  const int bid = blockIdx.x;
  const int t = threadIdx.x;
  if (bid >= 11264) {
    int i = (bid - 11264) * 256 + t;
    if (i < E) atomicAdd(&deg[col[i]], 1);
    return;
  }
  const float* in; ushort_t* out; int R, C, lb;
  if (bid < 1024)       { in = W1; out = W1t; R = 512;  C = 2048; lb = bid; }
  else if (bid < 5120)  { in = W3; out = W3t; R = 2048; C = 2048; lb = bid - 1024; }
  else if (bid < 10240) { in = W6; out = W6t; R = 2560; C = 2048; lb = bid - 5120; }
  else                  { in = W8; out = W8t; R = 2048; C = 512;  lb = bid - 10240; }
  __shared__ float tile[32][33];
  const int tx = t & 31, ty = t >> 5;
  const int nrt = R >> 5;
  const int r0 = (lb % nrt) * 32, c0 = (lb / nrt) * 32;
#pragma unroll
  for (int i = 0; i < 4; ++i)
    tile[ty + 8 * i][tx] = in[(size_t)(r0 + ty + 8 * i) * C + c0 + tx];
  __syncthreads();
#pragma unroll
  for (int i = 0; i < 4; ++i)
    out[(size_t)(c0 + ty + 8 * i) * R + r0 + tx] = f2bf(tile[tx][ty + 8 * i]);
}

// ---------------- CSR build: prefix scan, fill
__global__ __launch_bounds__(1024)
void prefix_kernel(const int* __restrict__ cnt, int* __restrict__ start,
                   int* __restrict__ cursor, int N) {
  const int t = threadIdx.x;
  const int chunk = (N + 1023) >> 10;
  const int base = t * chunk;
  int s = 0;
  for (int j = 0; j < chunk; ++j) {
    int i = base + j;
    s += (i < N) ? cnt[i] : 0;
  }
  const int lane = t & 63, wv = t >> 6;
  int scan = s;
#pragma unroll
  for (int o = 1; o < 64; o <<= 1) {
    int up = __shfl_up(scan, o);
    if (lane >= o) scan += up;
  }
  __shared__ int wsum[16];
  if (lane == 63) wsum[wv] = scan;
  __syncthreads();
  if (t == 0) {
    int acc = 0;
#pragma unroll
    for (int i2 = 0; i2 < 16; ++i2) { int v = wsum[i2]; wsum[i2] = acc; acc += v; }
  }
  __syncthreads();
  int run = wsum[wv] + (scan - s);
  for (int j = 0; j < chunk; ++j) {
    int i = base + j;
    if (i < N) {
      start[i] = run; cursor[i] = run;
      run += cnt[i];
    }
  }
}

__global__ __launch_bounds__(256)
void fill_csr(const int* __restrict__ col, int* __restrict__ cursor,
              int* __restrict__ eids, int E) {
  int i = blockIdx.x * 256 + threadIdx.x;
  if (i < E) {
    int p = atomicAdd(&cursor[col[i]], 1);
    eids[p] = i;
  }
}

// ---------------- gather-mean + build h0: block/node; per-wave contiguous quarter, x4 ILP
__global__ __launch_bounds__(256)
void gather_mean(const float* __restrict__ eattr, const int* __restrict__ start,
                 const int* __restrict__ deg, const int* __restrict__ eids,
                 const float* __restrict__ x, ushort_t* __restrict__ hcat, int N) {
  const int row = blockIdx.x;
  const int t = threadIdx.x;
  const int w = t >> 6, l = t & 63;
  const int s = start[row], d = deg[row];
  const float4* ea4 = (const float4*)eattr;
  float4 sum = make_float4(0.f, 0.f, 0.f, 0.f);
  const int chunk = (d + 3) >> 2;
  const int i0 = w * chunk;
  const int i1 = (d < i0 + chunk) ? d : i0 + chunk;
  int i = i0;
  for (; i + 4 <= i1; i += 4) {
    int e0 = eids[s + i], e1 = eids[s + i + 1], e2 = eids[s + i + 2], e3 = eids[s + i + 3];
    float4 v0 = ea4[(size_t)e0 * 64 + l];
    float4 v1 = ea4[(size_t)e1 * 64 + l];
    float4 v2 = ea4[(size_t)e2 * 64 + l];
    float4 v3 = ea4[(size_t)e3 * 64 + l];
    sum.x += v0.x + v1.x + v2.x + v3.x;
    sum.y += v0.y + v1.y + v2.y + v3.y;
    sum.z += v0.z + v1.z + v2.z + v3.z;
    sum.w += v0.w + v1.w + v2.w + v3.w;
  }
  for (; i < i1; ++i) {
    float4 v = ea4[(size_t)eids[s + i] * 64 + l];
    sum.x += v.x; sum.y += v.y; sum.z += v.z; sum.w += v.w;
  }
  __shared__ float4 part[4][64];
  part[w][l] = sum;
  __syncthreads();
  hcat[(size_t)row * 2560 + 2304 + t] = f2bf(x[(size_t)row * 256 + t]);
  if (w == 0) {
    float4 a = part[0][l], b = part[1][l], c = part[2][l], dd = part[3][l];
    const float inv = 1.f / fmaxf((float)d, 1.f);
    u16x4 o;
    o[0] = f2bf((a.x + b.x + c.x + dd.x) * inv);
    o[1] = f2bf((a.y + b.y + c.y + dd.y) * inv);
    o[2] = f2bf((a.z + b.z + c.z + dd.z) * inv);
    o[3] = f2bf((a.w + b.w + c.w + dd.w) * inv);
    *(u16x4*)(hcat + (size_t)row * 2560 + 2048 + l * 4) = o;
  }
}

// ---------------- LayerNorm IN PLACE over hcat[:, 0:2048] bf16 (row-local)
__global__ __launch_bounds__(256)
void ln_kernel(ushort_t* __restrict__ hcat, const float* __restrict__ g,
               const float* __restrict__ b) {
  const int row = blockIdx.x;
  const int t = threadIdx.x;
  ushort_t* p = hcat + (size_t)row * 2560 + t * 8;
  u16x8 raw = *(const u16x8*)p;
  float vv[8];
#pragma unroll
  for (int j = 0; j < 8; ++j) vv[j] = bf2f(raw[j]);
  float s = 0.f, ss = 0.f;
#pragma unroll
  for (int j = 0; j < 8; ++j) { s += vv[j]; ss += vv[j] * vv[j]; }
#pragma unroll
  for (int o = 32; o > 0; o >>= 1) {
    s += __shfl_xor(s, o);
    ss += __shfl_xor(ss, o);
  }
  __shared__ float red[8];
  int w = t >> 6, l = t & 63;
  if (l == 0) { red[w] = s; red[4 + w] = ss; }
  __syncthreads();
  s = red[0] + red[1] + red[2] + red[3];
  ss = red[4] + red[5] + red[6] + red[7];
  const float mu = s * (1.f / 2048.f);
  const float var = ss * (1.f / 2048.f) - mu * mu;
  const float rs = rsqrtf(var + 1e-5f);
  float4 g0 = *(const float4*)(g + t * 8);
  float4 g1 = *(const float4*)(g + t * 8 + 4);
  float4 b0 = *(const float4*)(b + t * 8);
  float4 b1 = *(const float4*)(b + t * 8 + 4);
  float gg[8] = {g0.x, g0.y, g0.z, g0.w, g1.x, g1.y, g1.z, g1.w};
  float bb[8] = {b0.x, b0.y, b0.z, b0.w, b1.x, b1.y, b1.z, b1.w};
  u16x8 o8;
#pragma unroll
  for (int j = 0; j < 8; ++j) o8[j] = f2bf((vv[j] - mu) * rs * gg[j] + bb[j]);
  *(u16x8*)p = o8;
}

#define SBAR() do { __builtin_amdgcn_sched_barrier(0); \
                    __builtin_amdgcn_s_barrier(); \
                    __builtin_amdgcn_sched_barrier(0); } while (0)

// ======================= 128x256 8-wave GEMM, BK=32, 2 blocks/CU =======================
// Measured-best structure (823us path). Single barrier + counted vmcnt(3)/K-tile,
// stage-first, swizzled LDS, swapped MFMA operands -> vectorized C-stores.
template <int RELU, int OUTBF>
__global__ __launch_bounds__(512, 4)
void gemm128(const ushort_t* __restrict__ A, int lda,
             const ushort_t* __restrict__ Bt,
             const float* __restrict__ bias,
             void* __restrict__ Cout, int ldc, int M, int K) {
  __shared__ __align__(16) ushort_t smem[36864];  // 72 KiB = 3 x 24 KiB
  char* sb = (char*)smem;
  const int t = threadIdx.x;

  const int nct = gridDim.x;
  const int nwg = nct * gridDim.y;
  const int flat = blockIdx.y * nct + blockIdx.x;
  const int xcd = flat & 7, loc = flat >> 3;
  const int q = nwg >> 3, r = nwg & 7;
  const int swz = (xcd < r ? xcd * (q + 1) : r * (q + 1) + (xcd - r) * q) + loc;
  const int row0 = (swz / nct) * 128;
  const int col0 = (swz % nct) * 256;

  const int wid = t >> 6, l = t & 63;
  const int wr = wid >> 2, wc = wid & 3;
  const int lr = l & 15, lk = l >> 4;

  const int srow = t >> 2;
  const int scol = ((t & 3) ^ ((t >> 2) & 3)) << 3;
  int ar = row0 + srow; if (ar > M - 1) ar = M - 1;
  const ushort_t* pa  = A + (size_t)ar * lda + scol;
  const ushort_t* pb0 = Bt + (size_t)(col0 + srow) * K + scol;
  const ushort_t* pb1 = pb0 + (size_t)128 * K;
  const int tb = t * 16;

  const int sx = ((lk ^ (lr & 3)) << 4);
  const int arow = (wr * 64 + lr) * 64 + sx;
  const int brow = 8192 + (wc * 64 + lr) * 64 + sx;

  f32x4 acc[4][4] = {};
  const int nk = K >> 5;

  {
    const int k1 = (nk > 1) ? 32 : 0;
    gload16((ushort_t*)(sb + 8192 + tb), pb0);
    gload16((ushort_t*)(sb + 16384 + tb), pb1);
    gload16((ushort_t*)(sb + 0 + tb), pa);
    gload16((ushort_t*)(sb + 24576 + 8192 + tb), pb0 + k1);
    gload16((ushort_t*)(sb + 24576 + 16384 + tb), pb1 + k1);
    gload16((ushort_t*)(sb + 24576 + 0 + tb), pa + k1);
  }
  asm volatile("s_waitcnt vmcnt(3)" ::: "memory");
  SBAR();

  int cO = 0, sO = 49152;
  for (int k = 0; k < nk; ++k) {
    const int kc2 = ((k + 2 < nk) ? k + 2 : nk - 1) << 5;

    gload16((ushort_t*)(sb + sO + 8192 + tb), pb0 + kc2);
    gload16((ushort_t*)(sb + sO + 16384 + tb), pb1 + kc2);
    gload16((ushort_t*)(sb + sO + 0 + tb), pa + kc2);

    bf16x8 a[4], b[4];
#pragma unroll
    for (int m = 0; m < 4; ++m)
      a[m] = *(const bf16x8*)(sb + cO + arow + m * 1024);
#pragma unroll
    for (int n = 0; n < 4; ++n)
      b[n] = *(const bf16x8*)(sb + cO + brow + n * 1024);

    __builtin_amdgcn_s_setprio(1);
#pragma unroll
    for (int m = 0; m < 4; ++m)
#pragma unroll
      for (int n = 0; n < 4; ++n)
        acc[m][n] = __builtin_amdgcn_mfma_f32_16x16x32_bf16(b[n], a[m], acc[m][n], 0, 0, 0);
    __builtin_amdgcn_s_setprio(0);

    asm volatile("s_waitcnt vmcnt(3)" ::: "memory");
    SBAR();

    cO = (cO == 49152) ? 0 : cO + 24576;
    sO = (sO == 49152) ? 0 : sO + 24576;
  }
  asm volatile("s_waitcnt vmcnt(0)" ::: "memory");

#pragma unroll
  for (int mi = 0; mi < 4; ++mi) {
    const int orow = row0 + wr * 64 + mi * 16 + lr;
    if (orow < M) {
#pragma unroll
      for (int nj = 0; nj < 4; ++nj) {
        const int cb = col0 + wc * 64 + nj * 16 + lk * 4;
        const float4 bv = *(const float4*)(bias + cb);
        f32x4 v = acc[mi][nj];
        float o0 = v[0] + bv.x, o1 = v[1] + bv.y, o2 = v[2] + bv.z, o3 = v[3] + bv.w;
        if (RELU) {
          o0 = fmaxf(o0, 0.f); o1 = fmaxf(o1, 0.f);
          o2 = fmaxf(o2, 0.f); o3 = fmaxf(o3, 0.f);
        }
        if (OUTBF) {
          bf16x4 o;
          o[0] = (__bf16)o0; o[1] = (__bf16)o1; o[2] = (__bf16)o2; o[3] = (__bf16)o3;
          *(bf16x4*)((ushort_t*)Cout + (size_t)orow * ldc + cb) = o;
        } else {
          float4 ov = make_float4(o0, o1, o2, o3);
          *(float4*)((float*)Cout + (size_t)orow * ldc + cb) = ov;
        }
      }
    }
  }
}

// ======================= 128x128 8-wave GEMM, BK=32, 3 blocks/CU (GEMM4) ==============
// BN=128: doubles the grid (628 blocks for N=512) and with 48 KiB LDS + ~76 VGPR runs
// 3 blocks/CU -> better CU fill and deeper cross-block overlap for the narrow GEMM.
// Same FIFO: 2 gloads/tile, single barrier + counted vmcnt(2)/K-tile.
template <int RELU, int OUTBF>
__global__ __launch_bounds__(512, 6)
void gemm128n(const ushort_t* __restrict__ A, int lda,
              const ushort_t* __restrict__ Bt,
              const float* __restrict__ bias,
              void* __restrict__ Cout, int ldc, int M, int K) {
  __shared__ __align__(16) ushort_t smem[24576];  // 48 KiB = 3 x 16 KiB
  char* sb = (char*)smem;
  const int t = threadIdx.x;

  const int nct = gridDim.x;
  const int nwg = nct * gridDim.y;
  const int flat = blockIdx.y * nct + blockIdx.x;
  const int xcd = flat & 7, loc = flat >> 3;
  const int q = nwg >> 3, r = nwg & 7;
  const int swz = (xcd < r ? xcd * (q + 1) : r * (q + 1) + (xcd - r) * q) + loc;
  const int row0 = (swz / nct) * 128;
  const int col0 = (swz % nct) * 128;

  const int wid = t >> 6, l = t & 63;
  const int wr = wid >> 2, wc = wid & 3;   // 2M x 4N, per-wave 64x32
  const int lr = l & 15, lk = l >> 4;

  const int srow = t >> 2;
  const int scol = ((t & 3) ^ ((t >> 2) & 3)) << 3;
  int ar = row0 + srow; if (ar > M - 1) ar = M - 1;
  const ushort_t* pa  = A + (size_t)ar * lda + scol;
  const ushort_t* pb0 = Bt + (size_t)(col0 + srow) * K + scol;
  const int tb = t * 16;

  const int sx = ((lk ^ (lr & 3)) << 4);
  const int arow = (wr * 64 + lr) * 64 + sx;            // + m*1024
  const int brow = 8192 + (wc * 32 + lr) * 64 + sx;     // + n*1024 (n<2)

  f32x4 acc[4][2] = {};
  const int nk = K >> 5;

  // prologue: tiles 0,1 (2 gloads each); drain to tile0 (vmcnt(2))
  {
    const int k1 = (nk > 1) ? 32 : 0;
    gload16((ushort_t*)(sb + 8192 + tb), pb0);
    gload16((ushort_t*)(sb + 0 + tb), pa);
    gload16((ushort_t*)(sb + 16384 + 8192 + tb), pb0 + k1);
    gload16((ushort_t*)(sb + 16384 + 0 + tb), pa + k1);
  }
  asm volatile("s_waitcnt vmcnt(2)" ::: "memory");
  SBAR();

  int cO = 0, sO = 32768;
  for (int k = 0; k < nk; ++k) {
    const int kc2 = ((k + 2 < nk) ? k + 2 : nk - 1) << 5;

    gload16((ushort_t*)(sb + sO + 8192 + tb), pb0 + kc2);
    gload16((ushort_t*)(sb + sO + 0 + tb), pa + kc2);

    bf16x8 a[4], b[2];
#pragma unroll
    for (int m = 0; m < 4; ++m)
      a[m] = *(const bf16x8*)(sb + cO + arow + m * 1024);
#pragma unroll
    for (int n = 0; n < 2; ++n)
      b[n] = *(const bf16x8*)(sb + cO + brow + n * 1024);

    __builtin_amdgcn_s_setprio(1);
#pragma unroll
    for (int m = 0; m < 4; ++m)
#pragma unroll
      for (int n = 0; n < 2; ++n)
        acc[m][n] = __builtin_amdgcn_mfma_f32_16x16x32_bf16(b[n], a[m], acc[m][n], 0, 0, 0);
    __builtin_amdgcn_s_setprio(0);

    asm volatile("s_waitcnt vmcnt(2)" ::: "memory");
    SBAR();

    cO = (cO == 32768) ? 0 : cO + 16384;
    sO = (sO == 32768) ? 0 : sO + 16384;
  }
  asm volatile("s_waitcnt vmcnt(0)" ::: "memory");

#pragma unroll
  for (int mi = 0; mi < 4; ++mi) {
    const int orow = row0 + wr * 64 + mi * 16 + lr;
    if (orow < M) {
#pragma unroll
      for (int nj = 0; nj < 2; ++nj) {
        const int cb = col0 + wc * 32 + nj * 16 + lk * 4;
        const float4 bv = *(const float4*)(bias + cb);
        f32x4 v = acc[mi][nj];
        float o0 = v[0] + bv.x, o1 = v[1] + bv.y, o2 = v[2] + bv.z, o3 = v[3] + bv.w;
        if (RELU) {
          o0 = fmaxf(o0, 0.f); o1 = fmaxf(o1, 0.f);
          o2 = fmaxf(o2, 0.f); o3 = fmaxf(o3, 0.f);
        }
        if (OUTBF) {
          bf16x4 o;
          o[0] = (__bf16)o0; o[1] = (__bf16)o1; o[2] = (__bf16)o2; o[3] = (__bf16)o3;
          *(bf16x4*)((ushort_t*)Cout + (size_t)orow * ldc + cb) = o;
        } else {
          float4 ov = make_float4(o0, o1, o2, o3);
          *(float4*)((float*)Cout + (size_t)orow * ldc + cb) = ov;
        }
      }
    }
  }
}

extern "C" void kernel_launch(void* const* d_in, const int* in_sizes, int n_in,
                              void* d_out, int out_size, void* d_ws, size_t ws_size,
                              hipStream_t stream) {
  (void)n_in; (void)out_size; (void)ws_size;
  const float* x     = (const float*)d_in[0];
  const int*   eidx  = (const int*)d_in[1];
  const float* eattr = (const float*)d_in[2];
  const float* W1 = (const float*)d_in[6];
  const float* b1 = (const float*)d_in[7];
  const float* W3 = (const float*)d_in[8];
  const float* b3 = (const float*)d_in[9];
  const float* lng = (const float*)d_in[10];
  const float* lnb = (const float*)d_in[11];
  const float* W6 = (const float*)d_in[12];
  const float* b6 = (const float*)d_in[13];
  const float* W8 = (const float*)d_in[14];
  const float* b8 = (const float*)d_in[15];

  const int N = in_sizes[0] / 256;  // 20000
  const int E = in_sizes[2] / 256;  // 640000
  const int* col = eidx + E;        // edge_index[1]

  char* ws = (char*)d_ws;
  size_t off = 0;
  ushort_t* hcat = (ushort_t*)(ws + off);  off += (size_t)N * 2560 * 2;  // [h5/h4 | agg | x] bf16
  ushort_t* h2   = (ushort_t*)(ws + off);  off += (size_t)N * 2048 * 2;  // also reused as h7
  ushort_t* W1t = (ushort_t*)(ws + off);   off += (size_t)2048 * 512 * 2;
  ushort_t* W3t = (ushort_t*)(ws + off);   off += (size_t)2048 * 2048 * 2;
  ushort_t* W6t = (ushort_t*)(ws + off);   off += (size_t)2048 * 2560 * 2;
  ushort_t* W8t = (ushort_t*)(ws + off);   off += (size_t)512 * 2048 * 2;
  int* deg    = (int*)(ws + off);  off += (size_t)N * 4;
  int* startp = (int*)(ws + off);  off += (size_t)N * 4;
  int* cursor = (int*)(ws + off);  off += (size_t)N * 4;
  int* eids   = (int*)(ws + off);  off += (size_t)E * 4;

  hipMemsetAsync(deg, 0, (size_t)N * 4, stream);

  // fused: 4 weight transposes + edge histogram
  const int cntBlocks = (E + 255) / 256;
  prep_kernel<<<11264 + cntBlocks, 256, 0, stream>>>(W1, W3, W6, W8, W1t, W3t, W6t, W8t,
                                                     col, deg, E);
  prefix_kernel<<<1, 1024, 0, stream>>>(deg, startp, cursor, N);
  fill_csr<<<cntBlocks, 256, 0, stream>>>(col, cursor, eids, E);
  gather_mean<<<N, 256, 0, stream>>>(eattr, startp, deg, eids, x, hcat, N);

  const int Mt = (N + 127) / 128;   // 157
  // GEMM1: h0 [N,512] @ W1 -> h2 bf16 (ReLU)
  gemm128<1, 1><<<dim3(8, Mt), 512, 0, stream>>>(hcat + 2048, 2560, W1t, b1, h2, 2048, N, 512);
  // GEMM2: h2 @ W3 -> h4 bf16 (ReLU) DIRECTLY into hcat[:, 0:2048]
  gemm128<1, 1><<<dim3(8, Mt), 512, 0, stream>>>(h2, 2048, W3t, b3, hcat, 2560, N, 2048);
  // LN in place on hcat[:, 0:2048]
  ln_kernel<<<N, 256, 0, stream>>>(hcat, lng, lnb);
  // GEMM3: hcat [N,2560] @ W6 -> h7 bf16 (ReLU), reuse h2 buffer
  gemm128<1, 1><<<dim3(8, Mt), 512, 0, stream>>>(hcat, 2560, W6t, b6, h2, 2048, N, 2560);
  // GEMM4: h7 @ W8 -> out f32  [BN=128 variant, 3 blocks/CU, 628 blocks]
  gemm128n<0, 0><<<dim3(4, Mt), 512, 0, stream>>>(h2, 2048, W8t, b8, (float*)d_out, 512, N, 2048);
}